// Round 1
// baseline (67.200 us; speedup 1.0000x reference)
//
#include <hip/hip_runtime.h>
#include <hip/hip_bf16.h>
#include <math.h>

// DOSAConLoss: loss_loc factorizes (broadcast (N,1)/(N,) -> (N,N) mean = (ΣA)(ΣB)/N²)
// + P=100 contrastive pairs. Output: single f32 scalar.

#define NBLK 64
#define NTHR 256

__device__ __forceinline__ float iou_plain(float4 b1, float4 b2) {
    float b1x1 = b1.x - 0.5f * b1.z, b1x2 = b1.x + 0.5f * b1.z;
    float b1y1 = b1.y - 0.5f * b1.w, b1y2 = b1.y + 0.5f * b1.w;
    float b2x1 = b2.x - 0.5f * b2.z, b2x2 = b2.x + 0.5f * b2.z;
    float b2y1 = b2.y - 0.5f * b2.w, b2y2 = b2.y + 0.5f * b2.w;
    float iw = fmaxf(fminf(b1x2, b2x2) - fmaxf(b1x1, b2x1), 0.0f);
    float ih = fmaxf(fminf(b1y2, b2y2) - fmaxf(b1y1, b2y1), 0.0f);
    float inter = iw * ih;
    float uni = b1.z * b1.w + b2.z * b2.w - inter + 1e-7f;
    return inter / uni;
}

__device__ __forceinline__ float iou_ciou(float4 b1, float4 b2) {
    float b1x1 = b1.x - 0.5f * b1.z, b1x2 = b1.x + 0.5f * b1.z;
    float b1y1 = b1.y - 0.5f * b1.w, b1y2 = b1.y + 0.5f * b1.w;
    float b2x1 = b2.x - 0.5f * b2.z, b2x2 = b2.x + 0.5f * b2.z;
    float b2y1 = b2.y - 0.5f * b2.w, b2y2 = b2.y + 0.5f * b2.w;
    float iw = fmaxf(fminf(b1x2, b2x2) - fmaxf(b1x1, b2x1), 0.0f);
    float ih = fmaxf(fminf(b1y2, b2y2) - fmaxf(b1y1, b2y1), 0.0f);
    float inter = iw * ih;
    float uni = b1.z * b1.w + b2.z * b2.w - inter + 1e-7f;
    float iou = inter / uni;
    float cw = fmaxf(b1x2, b2x2) - fminf(b1x1, b2x1);
    float ch = fmaxf(b1y2, b2y2) - fminf(b1y1, b2y1);
    float c2 = cw * cw + ch * ch + 1e-7f;
    // rho2 = ((2x2-2x1)^2 + (2y2-2y1)^2)/4 = (x2-x1)^2 + (y2-y1)^2
    float dx = b2.x - b1.x, dy = b2.y - b1.y;
    float rho2 = dx * dx + dy * dy;
    float dat = atanf(b2.z / b2.w) - atanf(b1.z / b1.w);
    const float four_over_pi2 = 0.40528473456935108578f; // 4/pi^2
    float v = four_over_pi2 * dat * dat;
    float alpha = v / (v - iou + (1.0f + 1e-7f));
    return iou - (rho2 / c2 + v * alpha);
}

__global__ __launch_bounds__(NTHR) void partials_kernel(
    const float4* __restrict__ pred, const float4* __restrict__ targ,
    const float* __restrict__ emb, const float* __restrict__ dens,
    const int* __restrict__ idx, float* __restrict__ ws, int N, int P) {
    int tid = threadIdx.x;
    int gtid = blockIdx.x * NTHR + tid;
    int lane = tid & 63;

    float sA = 0.0f, sB = 0.0f, sC = 0.0f;

    // --- loc part: grid-stride over N boxes ---
    for (int i = gtid; i < N; i += NBLK * NTHR) {
        float4 pb = pred[i];
        float4 tb = targ[i];
        float iou = iou_ciou(pb, tb);
        float om = 1.0f - iou;              // >= 0 always
        float saf = om * om * sqrtf(om);    // om^2.5
        float hw = 1.0f / (1.0f + expf(5.0f * iou - 2.5f)); // sigmoid(5*(0.5-iou))
        sA += (1.0f + 1.2f * dens[i]) * hw * saf;
        sB += 1.0f / (tb.z * tb.w + 1e-7f);
    }

    // --- contrastive part: one wave per pair ---
    int wid = gtid >> 6;   // global wave id; 256 waves total, P=100 used
    if (wid < P) {
        int i0 = idx[2 * wid];
        int i1 = idx[2 * wid + 1];
        const float4* e0 = (const float4*)(emb + (size_t)i0 * 256);
        const float4* e1 = (const float4*)(emb + (size_t)i1 * 256);
        float4 a = e0[lane];
        float4 b = e1[lane];
        float dx = a.x - b.x, dy = a.y - b.y, dz = a.z - b.z, dw = a.w - b.w;
        float d2 = dx * dx + dy * dy + dz * dz + dw * dw;
        #pragma unroll
        for (int o = 32; o > 0; o >>= 1) d2 += __shfl_xor(d2, o);
        if (lane == 0) {
            float dist = sqrtf(d2);
            float pl = fmaxf(1.0f - dist, 0.0f);
            pl = pl * pl;
            float piou = iou_plain(pred[i0], pred[i1]);
            if (piou > 0.3f) sC += pl;
        }
    }

    // --- block reduction (4 waves) ---
    #pragma unroll
    for (int o = 32; o > 0; o >>= 1) {
        sA += __shfl_xor(sA, o);
        sB += __shfl_xor(sB, o);
        sC += __shfl_xor(sC, o);
    }
    __shared__ float lred[4][3];
    if (lane == 0) {
        int w = tid >> 6;
        lred[w][0] = sA; lred[w][1] = sB; lred[w][2] = sC;
    }
    __syncthreads();
    if (tid == 0) {
        float a = 0.0f, b = 0.0f, c = 0.0f;
        #pragma unroll
        for (int w = 0; w < 4; w++) { a += lred[w][0]; b += lred[w][1]; c += lred[w][2]; }
        ws[blockIdx.x] = a;
        ws[NBLK + blockIdx.x] = b;
        ws[2 * NBLK + blockIdx.x] = c;
    }
}

__global__ __launch_bounds__(64) void finalize_kernel(
    const float* __restrict__ ws, float* __restrict__ out, float n2, float pdenom) {
    int t = threadIdx.x;
    float a = ws[t];
    float b = ws[NBLK + t];
    float c = ws[2 * NBLK + t];
    #pragma unroll
    for (int o = 32; o > 0; o >>= 1) {
        a += __shfl_xor(a, o);
        b += __shfl_xor(b, o);
        c += __shfl_xor(c, o);
    }
    if (t == 0) {
        out[0] = (a * b) / n2 + 0.5f * c / pdenom;
    }
}

extern "C" void kernel_launch(void* const* d_in, const int* in_sizes, int n_in,
                              void* d_out, int out_size, void* d_ws, size_t ws_size,
                              hipStream_t stream) {
    const float4* pred = (const float4*)d_in[0];
    const float4* targ = (const float4*)d_in[1];
    const float* emb   = (const float*)d_in[2];
    const float* dens  = (const float*)d_in[3];
    const int* idx     = (const int*)d_in[4];
    float* out = (float*)d_out;
    float* ws  = (float*)d_ws;

    int N = in_sizes[0] / 4;   // 8192
    int P = in_sizes[4] / 2;   // 100

    partials_kernel<<<NBLK, NTHR, 0, stream>>>(pred, targ, emb, dens, idx, ws, N, P);
    float n2 = (float)N * (float)N;
    float pdenom = (float)P + 1e-7f;
    finalize_kernel<<<1, 64, 0, stream>>>(ws, out, n2, pdenom);
}